// Round 1
// baseline (455.213 us; speedup 1.0000x reference)
//
#include <hip/hip_runtime.h>
#include <math.h>

#define BATCH 128
#define NINS  4096
#define NHID  128
#define KH    64
#define TILES_PER_BLOCK 2                         // 2 x 64 = 128 n per block
#define NBLK_PER_B (NINS / (64 * TILES_PER_BLOCK)) // 32
#define PART_STRIDE (NHID + 2)                    // m, L, out[128]

// --------------------------------------------------------------------------
// Kernel A: c[b][k] = b1[k] + sum_d inputs[b,index,d] * W1[d][k]
// (the "own" half of the first linear layer, constant across n per batch)
// --------------------------------------------------------------------------
__global__ void precompute_c(const float* __restrict__ inputs,
                             const int* __restrict__ index_p,
                             const float* __restrict__ W1,
                             const float* __restrict__ b1,
                             float* __restrict__ c) {
    const int b = blockIdx.x;
    const int k = threadIdx.x;   // 0..63
    const int idx = index_p[0];
    const float* own = inputs + ((size_t)b * NINS + idx) * NHID;
    float acc = b1[k];
    for (int d = 0; d < NHID; ++d)
        acc = fmaf(own[d], W1[d * KH + k], acc);   // W1[d*64+k]: coalesced
    c[b * KH + k] = acc;
}

// --------------------------------------------------------------------------
// Kernel B: main pass. One wave per block; lane l = one n.
// h[k] accumulators in VGPRs, W1 rows via scalar loads (wave-uniform).
// Online softmax + weighted-sum partial per block.
// --------------------------------------------------------------------------
__global__ __launch_bounds__(64)
void att_partial(const float* __restrict__ inputs,
                 const float* __restrict__ W1,
                 const float* __restrict__ W2,
                 const float* __restrict__ b2_p,
                 const float* __restrict__ c,
                 float* __restrict__ part) {
    const int lane = threadIdx.x;           // 0..63
    const int b    = blockIdx.y;            // batch
    const float* Wb    = W1 + (size_t)NHID * KH;       // bottom rows d=128..255
    const float* xbase = inputs + (size_t)b * NINS * NHID;
    const float  b2v   = b2_p[0];

    float m_run = -INFINITY;
    float L_run = 0.0f;
    float o0 = 0.0f, o1 = 0.0f;             // out partials for d=lane, lane+64

    for (int t = 0; t < TILES_PER_BLOCK; ++t) {
        const int n0 = (blockIdx.x * TILES_PER_BLOCK + t) * 64;
        const float* xrow = xbase + (size_t)(n0 + lane) * NHID;

        float h[KH];
        #pragma unroll
        for (int k = 0; k < KH; ++k) h[k] = c[b * KH + k];   // uniform -> s_load

        // GEMM: h[k] += x[d] * Wb[d][k], d-chunks of 16
        for (int dc = 0; dc < NHID; dc += 16) {
            float4 xv[4];
            #pragma unroll
            for (int i = 0; i < 4; ++i)
                xv[i] = *(const float4*)(xrow + dc + i * 4);
            const float* xs = (const float*)xv;
            #pragma unroll
            for (int i = 0; i < 16; ++i) {
                const float xd = xs[i];
                const float* wrow = Wb + (size_t)(dc + i) * KH;  // uniform row
                #pragma unroll
                for (int k = 0; k < KH; ++k)
                    h[k] = fmaf(xd, wrow[k], h[k]);   // v_fmac v,s,v
            }
        }

        // att = b2 + sum_k relu(h[k]) * W2[k]
        float att = b2v;
        #pragma unroll
        for (int k = 0; k < KH; ++k)
            att = fmaf(fmaxf(h[k], 0.0f), W2[k], att);

        // wave max of att
        float m_t = att;
        #pragma unroll
        for (int off = 32; off; off >>= 1)
            m_t = fmaxf(m_t, __shfl_xor(m_t, off));

        const float M     = fmaxf(m_run, m_t);
        const float alpha = __expf(m_run - M);   // first tile: exp(-inf)=0
        o0 *= alpha; o1 *= alpha; L_run *= alpha;

        const float e = __expf(att - M);
        float se = e;
        #pragma unroll
        for (int off = 32; off; off >>= 1)
            se += __shfl_xor(se, off);
        L_run += se;

        // weighted sum over this tile: lane j accumulates d=j and d=j+64
        const float* xt = xbase + (size_t)n0 * NHID;
        for (int l = 0; l < 64; ++l) {
            const float el = __shfl(e, l);
            o0 = fmaf(el, xt[(size_t)l * NHID + lane],      o0);  // coalesced, L1/L2 hot
            o1 = fmaf(el, xt[(size_t)l * NHID + lane + 64], o1);
        }
        m_run = M;
    }

    float* p = part + (size_t)(b * gridDim.x + blockIdx.x) * PART_STRIDE;
    if (lane == 0) { p[0] = m_run; p[1] = L_run; }
    p[2 + lane]      = o0;
    p[2 + lane + 64] = o1;
}

// --------------------------------------------------------------------------
// Kernel C: merge 32 partials per batch -> out[b][d]
// --------------------------------------------------------------------------
__global__ void finalize(const float* __restrict__ part,
                         float* __restrict__ out) {
    const int b = blockIdx.x;
    const int d = threadIdx.x;   // 0..127
    const float* pb = part + (size_t)b * NBLK_PER_B * PART_STRIDE;

    float M = -INFINITY;
    for (int p = 0; p < NBLK_PER_B; ++p)
        M = fmaxf(M, pb[p * PART_STRIDE]);

    float S = 0.0f, acc = 0.0f;
    for (int p = 0; p < NBLK_PER_B; ++p) {
        const float sc = __expf(pb[p * PART_STRIDE] - M);
        S   = fmaf(sc, pb[p * PART_STRIDE + 1], S);
        acc = fmaf(sc, pb[p * PART_STRIDE + 2 + d], acc);
    }
    out[b * NHID + d] = acc / S;
}

// --------------------------------------------------------------------------
extern "C" void kernel_launch(void* const* d_in, const int* in_sizes, int n_in,
                              void* d_out, int out_size, void* d_ws, size_t ws_size,
                              hipStream_t stream) {
    const float* inputs = (const float*)d_in[0];
    const int*   index  = (const int*)  d_in[1];
    // d_in[2] = claims (unused by forward)
    const float* W1     = (const float*)d_in[3];
    const float* b1     = (const float*)d_in[4];
    const float* W2     = (const float*)d_in[5];
    const float* b2     = (const float*)d_in[6];
    float* out = (float*)d_out;

    float* c    = (float*)d_ws;                 // BATCH*KH floats = 32 KB
    float* part = c + BATCH * KH;               // BATCH*32*130 floats ~= 2.1 MB

    precompute_c<<<dim3(BATCH), dim3(64), 0, stream>>>(inputs, index, W1, b1, c);

    dim3 gB(NBLK_PER_B, BATCH);                 // 32 x 128 = 4096 blocks, 1 wave each
    att_partial<<<gB, dim3(64), 0, stream>>>(inputs, W1, W2, b2, c, part);

    finalize<<<dim3(BATCH), dim3(NHID), 0, stream>>>(part, out);
}